// Round 1
// baseline (835.756 us; speedup 1.0000x reference)
//
#include <hip/hip_runtime.h>

typedef unsigned short u16;
typedef unsigned int u32;
typedef __attribute__((ext_vector_type(8))) short bf16x8;
typedef __attribute__((ext_vector_type(4))) float f32x4;

__device__ __forceinline__ u16 f2bf(float f) {
  u32 u = __float_as_uint(f);
  return (u16)((u + 0x7fffu + ((u >> 16) & 1u)) >> 16);
}
__device__ __forceinline__ float bf2f(u16 h) {
  return __uint_as_float(((u32)h) << 16);
}

// ---------------------------------------------------------------------------
// Generic MFMA GEMM: C[M x Ntot] = A[M x K](f32, row-major) * Bt[Ntot x K](bf16)^T
// block tile 128 rows x 256 cols, 4 waves (each 64x128), BK = 64.
// grid.x = M/128, grid.y = Ntot/256.
// ---------------------------------------------------------------------------
template<int K, bool OUT_BF16>
__global__ __launch_bounds__(256) void gemm_mfma(
    const float* __restrict__ A, const u16* __restrict__ Bt,
    void* __restrict__ Cv, int Ntot) {
  constexpr int LD = 72;  // 64 + 8 pad: 144B row stride, 16B aligned, 2-way-bank only
  __shared__ __align__(16) u16 Asm[128 * LD];
  __shared__ __align__(16) u16 Bsm[256 * LD];
  const int tid = threadIdx.x;
  const int lane = tid & 63;
  const int w = tid >> 6;
  const int m = lane & 15;
  const int q = lane >> 4;
  const int wrow = (w & 1) * 64;
  const int wcol = (w >> 1) * 128;
  const long rowbase = (long)blockIdx.x * 128;
  const long colbase = (long)blockIdx.y * 256;
  f32x4 acc[4][8];
#pragma unroll
  for (int r = 0; r < 4; ++r)
#pragma unroll
    for (int c = 0; c < 8; ++c) acc[r][c] = (f32x4){0.f, 0.f, 0.f, 0.f};

  for (int kc = 0; kc < K / 64; ++kc) {
    const int kb = kc * 64;
    // stage A chunk: 128 rows x 64 k, f32 -> bf16
#pragma unroll
    for (int it = 0; it < 8; ++it) {
      int f = it * 256 + tid;
      int r = f >> 4, c4 = (f & 15) * 4;
      float4 v = *(const float4*)(A + (rowbase + r) * K + kb + c4);
      ushort4 h;
      h.x = f2bf(v.x); h.y = f2bf(v.y); h.z = f2bf(v.z); h.w = f2bf(v.w);
      *(ushort4*)&Asm[r * LD + c4] = h;
    }
    // stage B chunk: 256 cols x 64 k (already bf16, transposed)
#pragma unroll
    for (int it = 0; it < 8; ++it) {
      int f = it * 256 + tid;
      int c = f >> 3, k8 = (f & 7) * 8;
      *(uint4*)&Bsm[c * LD + k8] =
          *(const uint4*)(Bt + (colbase + c) * K + kb + k8);
    }
    __syncthreads();
#pragma unroll
    for (int s = 0; s < 2; ++s) {
      const int ko = s * 32 + q * 8;
      bf16x8 av[4], bv[8];
#pragma unroll
      for (int r = 0; r < 4; ++r)
        av[r] = *(const bf16x8*)&Asm[(wrow + r * 16 + m) * LD + ko];
#pragma unroll
      for (int c = 0; c < 8; ++c)
        bv[c] = *(const bf16x8*)&Bsm[(wcol + c * 16 + m) * LD + ko];
#pragma unroll
      for (int r = 0; r < 4; ++r)
#pragma unroll
        for (int c = 0; c < 8; ++c)
          acc[r][c] = __builtin_amdgcn_mfma_f32_16x16x32_bf16(
              av[r], bv[c], acc[r][c], 0, 0, 0);
    }
    __syncthreads();
  }
  // epilogue: C/D layout col=lane&15, row=(lane>>4)*4+reg  [m89/m91 verified]
#pragma unroll
  for (int r = 0; r < 4; ++r)
#pragma unroll
    for (int c = 0; c < 8; ++c)
#pragma unroll
      for (int g = 0; g < 4; ++g) {
        long gr = rowbase + wrow + r * 16 + q * 4 + g;
        long gc = colbase + wcol + c * 16 + m;
        float v = acc[r][c][g];
        if (OUT_BF16) ((u16*)Cv)[gr * Ntot + gc] = f2bf(v);
        else          ((float*)Cv)[gr * Ntot + gc] = v;
      }
}

// ---------------------------------------------------------------------------
// Build transposed bf16 weight tables in workspace.
// BtE1[512][256]: cols 0..255 fuse1_w[d:], 256..511 fc1_w0[2d:]
// BtE2[512][256]: fuse2_w[d:], fc2_w0[2d:]
// BtW0[512][256]: weight, align_lin
// BtLoop[1536][256]: fuse1[:d], fuse2[:d], fc1[:d], fc1[d:2d], fc2[:d], fc2[d:2d]
// BtFc3[256][512]: fc3_w (K=512)
// ---------------------------------------------------------------------------
__global__ __launch_bounds__(256) void prep_bt(
    const float* __restrict__ weight, const float* __restrict__ align_lin,
    const float* __restrict__ fuse1_w, const float* __restrict__ fuse2_w,
    const float* __restrict__ fc1_w0, const float* __restrict__ fc2_w0,
    const float* __restrict__ fc3_w,
    u16* BtE1, u16* BtE2, u16* BtW0, u16* BtLoop, u16* BtFc3) {
  int g = blockIdx.x * 256 + threadIdx.x;  // 0..917503
  float v;
  u16* dst;
  if (g < 131072) {
    int c = g >> 8, k = g & 255;
    v = (c < 256) ? fuse1_w[(256 + k) * 256 + c]
                  : fc1_w0[(512 + k) * 256 + (c - 256)];
    dst = BtE1 + g;
  } else if (g < 262144) {
    int t = g - 131072;
    int c = t >> 8, k = t & 255;
    v = (c < 256) ? fuse2_w[(256 + k) * 256 + c]
                  : fc2_w0[(512 + k) * 256 + (c - 256)];
    dst = BtE2 + t;
  } else if (g < 393216) {
    int t = g - 262144;
    int c = t >> 8, k = t & 255;
    v = (c < 256) ? weight[k * 256 + c] : align_lin[k * 256 + (c - 256)];
    dst = BtW0 + t;
  } else if (g < 786432) {
    int t = g - 393216;
    int c = t >> 8, k = t & 255;
    int seg = c >> 8, cc = c & 255;
    if      (seg == 0) v = fuse1_w[k * 256 + cc];
    else if (seg == 1) v = fuse2_w[k * 256 + cc];
    else if (seg == 2) v = fc1_w0[k * 256 + cc];
    else if (seg == 3) v = fc1_w0[(256 + k) * 256 + cc];
    else if (seg == 4) v = fc2_w0[k * 256 + cc];
    else               v = fc2_w0[(256 + k) * 256 + cc];
    dst = BtLoop + t;
  } else {
    int t = g - 786432;  // [256][512]
    int c = t >> 9, k = t & 511;
    v = fc3_w[k * 256 + c];
    dst = BtFc3 + t;
  }
  *dst = f2bf(v);
}

// ---------------------------------------------------------------------------
// out_buf = relu(T0[:, :256])
// ---------------------------------------------------------------------------
__global__ __launch_bounds__(256) void relu0_kernel(const float* __restrict__ T0,
                                                    float* __restrict__ outb) {
  long r = blockIdx.x;
  int d = threadIdx.x;
  outb[r * 256 + d] = fmaxf(T0[r * 512 + d], 0.f);
}

// ---------------------------------------------------------------------------
// SelfAlignment: per (b,i): logits_j = ta_i . text_j + maskadd; softmax;
// outss = (p @ text) * mask_i + align_bias.  128 threads/block, grid = B*N.
// ---------------------------------------------------------------------------
__global__ __launch_bounds__(128) void align_kernel(
    const float* __restrict__ text, const float* __restrict__ T0,
    const float* __restrict__ textmask, const float* __restrict__ align_bias,
    float* __restrict__ outss) {
  const int bi = blockIdx.x;
  const int b = bi >> 7;
  const int tid = threadIdx.x;
  __shared__ float ta[256];
  __shared__ float pr[128];
  __shared__ float red[128];
  ta[tid]       = T0[(long)bi * 512 + 256 + tid];
  ta[tid + 128] = T0[(long)bi * 512 + 384 + tid];
  __syncthreads();
  const float* trow = text + (long)(b * 128 + tid) * 256;
  float dot = 0.f;
  for (int d = 0; d < 256; d += 4) {
    float4 t4 = *(const float4*)(trow + d);
    dot += t4.x * ta[d] + t4.y * ta[d + 1] + t4.z * ta[d + 2] + t4.w * ta[d + 3];
  }
  float logit = dot + (1.0f - textmask[b * 128 + tid]) * -1e20f;
  pr[tid] = logit;
  red[tid] = logit;
  __syncthreads();
  for (int off = 64; off; off >>= 1) {
    if (tid < off) red[tid] = fmaxf(red[tid], red[tid + off]);
    __syncthreads();
  }
  float mx = red[0];
  __syncthreads();
  float e = __expf(pr[tid] - mx);
  red[tid] = e;
  __syncthreads();
  for (int off = 64; off; off >>= 1) {
    if (tid < off) red[tid] += red[tid + off];
    __syncthreads();
  }
  float inv = 1.0f / red[0];
  __syncthreads();
  pr[tid] = e * inv;
  __syncthreads();
  const float mi = textmask[bi];
  for (int h = 0; h < 2; ++h) {
    int d = tid + h * 128;
    float s = 0.f;
    for (int j = 0; j < 128; ++j)
      s += pr[j] * text[(long)(b * 128 + j) * 256 + d];
    outss[(long)bi * 256 + d] = s * mi + align_bias[d];
  }
}

// ---------------------------------------------------------------------------
// Fused gate/aggregate, per (b,i). 256 thr = 4 waves, wave handles j = w,w+4,..
// lane holds d = 4*lane .. 4*lane+3.
// P row layout [1536]: ofu1|ofu2|ti1|tj1|ti2|tj2 (256 each)
// E row layout [512]: fuse|fc (bf16)
// OU12[bi][512] = out1 | out2 (already / denom)
// ---------------------------------------------------------------------------
__global__ __launch_bounds__(256) void fused_gate(
    const u16* __restrict__ E1, const u16* __restrict__ E2,
    const float* __restrict__ P, const float* __restrict__ adj1,
    const float* __restrict__ adj2, const float* __restrict__ fc1w1,
    const float* __restrict__ fc1b1, const float* __restrict__ fc2w1,
    const float* __restrict__ fc2b1, float* __restrict__ OU12) {
  const int tid = threadIdx.x, lane = tid & 63, w = tid >> 6;
  const int bi = blockIdx.x;
  const int b = bi >> 7, i = bi & 127;
  const int l4 = lane * 4;
  const float4 w1v = *(const float4*)(fc1w1 + l4);
  const float4 w2v = *(const float4*)(fc2w1 + l4);
  const float b1 = fc1b1[0], b2 = fc2b1[0];
  const long rowi = (long)bi * 1536;
  const float4 ti1 = *(const float4*)(P + rowi + 512 + l4);
  const float4 ti2 = *(const float4*)(P + rowi + 1024 + l4);
  float4 acc1 = {0.f, 0.f, 0.f, 0.f}, acc2 = {0.f, 0.f, 0.f, 0.f};
  float da1 = 0.f, da2 = 0.f;
  const long ebase = ((long)b * 16384 + (long)i * 128) * 512;
  const int abase = b * 16384 + i * 128;
  for (int j = w; j < 128; j += 4) {
    const long er = ebase + (long)j * 512;
    ushort4 e1f = *(const ushort4*)(E1 + er + l4);
    ushort4 e1c = *(const ushort4*)(E1 + er + 256 + l4);
    ushort4 e2f = *(const ushort4*)(E2 + er + l4);
    ushort4 e2c = *(const ushort4*)(E2 + er + 256 + l4);
    const long rowj = (long)(b * 128 + j) * 1536;
    float4 of1 = *(const float4*)(P + rowj + l4);
    float4 of2 = *(const float4*)(P + rowj + 256 + l4);
    float4 tj1 = *(const float4*)(P + rowj + 768 + l4);
    float4 tj2 = *(const float4*)(P + rowj + 1280 + l4);
    float a1 = adj1[abase + j], a2 = adj2[abase + j];
    // gate dot-products (relu then dot with fc*_w1), partial per lane
    float z1, z2;
    {
      float r0 = fmaxf(ti1.x + tj1.x + bf2f(e1c.x), 0.f);
      float r1 = fmaxf(ti1.y + tj1.y + bf2f(e1c.y), 0.f);
      float r2 = fmaxf(ti1.z + tj1.z + bf2f(e1c.z), 0.f);
      float r3 = fmaxf(ti1.w + tj1.w + bf2f(e1c.w), 0.f);
      z1 = r0 * w1v.x + r1 * w1v.y + r2 * w1v.z + r3 * w1v.w;
      float s0 = fmaxf(ti2.x + tj2.x + bf2f(e2c.x), 0.f);
      float s1_ = fmaxf(ti2.y + tj2.y + bf2f(e2c.y), 0.f);
      float s2_ = fmaxf(ti2.z + tj2.z + bf2f(e2c.z), 0.f);
      float s3_ = fmaxf(ti2.w + tj2.w + bf2f(e2c.w), 0.f);
      z2 = s0 * w2v.x + s1_ * w2v.y + s2_ * w2v.z + s3_ * w2v.w;
    }
#pragma unroll
    for (int off = 32; off; off >>= 1) {
      z1 += __shfl_xor(z1, off);
      z2 += __shfl_xor(z2, off);
    }
    float s1 = a1 / (1.f + __expf(-(z1 + b1)));
    float s2 = a2 / (1.f + __expf(-(z2 + b2)));
    acc1.x += s1 * fmaxf(of1.x + bf2f(e1f.x), 0.f);
    acc1.y += s1 * fmaxf(of1.y + bf2f(e1f.y), 0.f);
    acc1.z += s1 * fmaxf(of1.z + bf2f(e1f.z), 0.f);
    acc1.w += s1 * fmaxf(of1.w + bf2f(e1f.w), 0.f);
    acc2.x += s2 * fmaxf(of2.x + bf2f(e2f.x), 0.f);
    acc2.y += s2 * fmaxf(of2.y + bf2f(e2f.y), 0.f);
    acc2.z += s2 * fmaxf(of2.z + bf2f(e2f.z), 0.f);
    acc2.w += s2 * fmaxf(of2.w + bf2f(e2f.w), 0.f);
    da1 += a1;
    da2 += a2;
  }
  __shared__ float red[4][512];
  __shared__ float dred[4][2];
  *(float4*)&red[w][l4] = acc1;
  *(float4*)&red[w][256 + l4] = acc2;
  if (lane == 0) { dred[w][0] = da1; dred[w][1] = da2; }
  __syncthreads();
  float o1 = red[0][tid] + red[1][tid] + red[2][tid] + red[3][tid];
  float o2 = red[0][256 + tid] + red[1][256 + tid] + red[2][256 + tid] + red[3][256 + tid];
  float d1 = dred[0][0] + dred[1][0] + dred[2][0] + dred[3][0] + 1.f;
  float d2 = dred[0][1] + dred[1][1] + dred[2][1] + dred[3][1] + 1.f;
  OU12[(long)bi * 512 + tid] = o1 / d1;
  OU12[(long)bi * 512 + 256 + tid] = o2 / d2;
}

// ---------------------------------------------------------------------------
// out = layernorm(relu(Y) + prev + bias) * gamma + beta; one row per block.
// ---------------------------------------------------------------------------
__global__ __launch_bounds__(256) void ln_kernel(
    const float* __restrict__ Y, const float* __restrict__ prev,
    const float* __restrict__ bias, const float* __restrict__ gamma,
    const float* __restrict__ beta, float* __restrict__ dst) {
  const int row = blockIdx.x, tid = threadIdx.x, lane = tid & 63, w = tid >> 6;
  const long idx = (long)row * 256 + tid;
  float v = fmaxf(Y[idx], 0.f) + prev[idx] + bias[tid];
  float s = v;
#pragma unroll
  for (int off = 32; off; off >>= 1) s += __shfl_xor(s, off);
  __shared__ float wsA[4], wsB[4];
  if (lane == 0) wsA[w] = s;
  __syncthreads();
  float mean = (wsA[0] + wsA[1] + wsA[2] + wsA[3]) * (1.0f / 256.0f);
  float c = v - mean;
  float s2 = c * c;
#pragma unroll
  for (int off = 32; off; off >>= 1) s2 += __shfl_xor(s2, off);
  if (lane == 0) wsB[w] = s2;
  __syncthreads();
  float var = (wsB[0] + wsB[1] + wsB[2] + wsB[3]) * (1.0f / 256.0f);
  dst[idx] = c * rsqrtf(var + 1e-5f) * gamma[tid] + beta[tid];
}

// ---------------------------------------------------------------------------
extern "C" void kernel_launch(void* const* d_in, const int* in_sizes, int n_in,
                              void* d_out, int out_size, void* d_ws, size_t ws_size,
                              hipStream_t stream) {
  const float* text      = (const float*)d_in[0];
  const float* adj1      = (const float*)d_in[1];
  const float* adj2      = (const float*)d_in[2];
  const float* edge1     = (const float*)d_in[3];
  const float* edge2     = (const float*)d_in[4];
  const float* textmask  = (const float*)d_in[5];
  const float* weight    = (const float*)d_in[6];
  const float* bias      = (const float*)d_in[7];
  const float* gamma     = (const float*)d_in[8];
  const float* beta      = (const float*)d_in[9];
  const float* fuse1_w   = (const float*)d_in[10];
  const float* fuse2_w   = (const float*)d_in[11];
  const float* fc3_w     = (const float*)d_in[12];
  const float* fc1_w0    = (const float*)d_in[13];
  const float* fc1_w1    = (const float*)d_in[14];
  const float* fc1_b1    = (const float*)d_in[15];
  const float* fc2_w0    = (const float*)d_in[16];
  const float* fc2_w1    = (const float*)d_in[17];
  const float* fc2_b1    = (const float*)d_in[18];
  const float* align_lin = (const float*)d_in[19];
  const float* align_bias= (const float*)d_in[20];
  float* outF = (float*)d_out;          // out: [0,262144), outss: [262144,524288)

  char* w8 = (char*)d_ws;
  u16*  E1    = (u16*)w8;                       // 131072 x 512 bf16 (128 MB)
  u16*  E2    = E1 + (long)67108864;            // 128 MB
  float* P    = (float*)(w8 + 268435456);       // 1024 x 1536 f32
  float* T0   = P + 1572864;                    // 1024 x 512 f32
  float* OU12 = T0 + 524288;                    // 1024 x 512 f32
  float* outb = OU12 + 524288;                  // 1024 x 256 f32
  float* Yb   = outb + 262144;                  // 1024 x 256 f32
  u16* BtE1   = (u16*)(Yb + 262144);            // 512 x 256
  u16* BtE2   = BtE1 + 131072;
  u16* BtW0   = BtE2 + 131072;
  u16* BtLoop = BtW0 + 131072;                  // 1536 x 256
  u16* BtFc3  = BtLoop + 393216;                // 256 x 512

  // 1) transposed bf16 weight tables
  prep_bt<<<3584, 256, 0, stream>>>(weight, align_lin, fuse1_w, fuse2_w,
                                    fc1_w0, fc2_w0, fc3_w,
                                    BtE1, BtE2, BtW0, BtLoop, BtFc3);
  // 2) edge projections (loop-invariant), bf16 out
  gemm_mfma<256, true><<<dim3(1024, 2), 256, 0, stream>>>(edge1, BtE1, E1, 512);
  gemm_mfma<256, true><<<dim3(1024, 2), 256, 0, stream>>>(edge2, BtE2, E2, 512);
  // 3) T0 = text @ [weight | align_lin]
  gemm_mfma<256, false><<<dim3(8, 2), 256, 0, stream>>>(text, BtW0, T0, 512);
  relu0_kernel<<<1024, 256, 0, stream>>>(T0, outb);
  // 4) self-alignment -> outss
  align_kernel<<<1024, 128, 0, stream>>>(text, T0, textmask, align_bias,
                                         outF + 262144);
  // 5) K = 3 GCN iterations
  for (int it = 0; it < 3; ++it) {
    gemm_mfma<256, false><<<dim3(8, 6), 256, 0, stream>>>(outb, BtLoop, P, 1536);
    fused_gate<<<1024, 256, 0, stream>>>(E1, E2, P, adj1, adj2, fc1_w1, fc1_b1,
                                         fc2_w1, fc2_b1, OU12);
    gemm_mfma<512, false><<<dim3(8, 1), 256, 0, stream>>>(OU12, BtFc3, Yb, 256);
    ln_kernel<<<1024, 256, 0, stream>>>(Yb, outb, bias, gamma, beta,
                                        (it == 2) ? outF : outb);
  }
}

// Round 2
// 764.204 us; speedup vs baseline: 1.0936x; 1.0936x over previous
//
#include <hip/hip_runtime.h>

typedef unsigned short u16;
typedef unsigned int u32;
typedef __attribute__((ext_vector_type(8))) short bf16x8;
typedef __attribute__((ext_vector_type(4))) float f32x4;
typedef __attribute__((ext_vector_type(16))) float f32x16;

__device__ __forceinline__ u16 f2bf(float f) {
  u32 u = __float_as_uint(f);
  return (u16)((u + 0x7fffu + ((u >> 16) & 1u)) >> 16);
}
__device__ __forceinline__ float bf2f(u16 h) {
  return __uint_as_float(((u32)h) << 16);
}

__device__ __forceinline__ void glds16(const void* g, void* l) {
  __builtin_amdgcn_global_load_lds(
      (const __attribute__((address_space(1))) unsigned int*)g,
      (__attribute__((address_space(3))) unsigned int*)l, 16, 0, 0);
}

// unpack 16 bf16 -> 16 f32 (two 16-B loads)
__device__ __forceinline__ f32x16 unpack16(const u16* p) {
  uint4 a = *(const uint4*)p, b = *(const uint4*)(p + 8);
  f32x16 r;
  r[0]  = __uint_as_float(a.x << 16); r[1]  = __uint_as_float(a.x & 0xffff0000u);
  r[2]  = __uint_as_float(a.y << 16); r[3]  = __uint_as_float(a.y & 0xffff0000u);
  r[4]  = __uint_as_float(a.z << 16); r[5]  = __uint_as_float(a.z & 0xffff0000u);
  r[6]  = __uint_as_float(a.w << 16); r[7]  = __uint_as_float(a.w & 0xffff0000u);
  r[8]  = __uint_as_float(b.x << 16); r[9]  = __uint_as_float(b.x & 0xffff0000u);
  r[10] = __uint_as_float(b.y << 16); r[11] = __uint_as_float(b.y & 0xffff0000u);
  r[12] = __uint_as_float(b.z << 16); r[13] = __uint_as_float(b.z & 0xffff0000u);
  r[14] = __uint_as_float(b.w << 16); r[15] = __uint_as_float(b.w & 0xffff0000u);
  return r;
}

// ---------------------------------------------------------------------------
// convert edge f32 [131072][256] -> bf16 tiled+swizzled [1024 rt][4 kc][128 r][64 k]
// element (r,k) of a tile stored at u16 idx r*64 + (k ^ ((r&7)*8))  (8-groups)
// one thread per 8-elem k-group; grid 16384 x 256.
// ---------------------------------------------------------------------------
__global__ __launch_bounds__(256) void convert_edge(
    const float* __restrict__ src, u16* __restrict__ dst) {
  int g = blockIdx.x * 256 + threadIdx.x;
  int kg = g & 7, r = (g >> 3) & 127, kc = (g >> 10) & 3, rt = g >> 12;
  const float* s = src + ((long)(rt * 128 + r) * 256 + kc * 64 + kg * 8);
  float4 a = *(const float4*)s, b = *(const float4*)(s + 4);
  ushort4 lo, hi;
  lo.x = f2bf(a.x); lo.y = f2bf(a.y); lo.z = f2bf(a.z); lo.w = f2bf(a.w);
  hi.x = f2bf(b.x); hi.y = f2bf(b.y); hi.z = f2bf(b.z); hi.w = f2bf(b.w);
  u16* d = dst + (long)rt * 65536 + kc * 16384 + r * 64 + (kg ^ (r & 7)) * 8;
  *(ushort4*)d = lo;
  *(ushort4*)(d + 4) = hi;
}

// ---------------------------------------------------------------------------
// Edge GEMM: E[131072 x 512] = A_tiled(bf16) * Bt_tiled(bf16)^T, K=256.
// 128x128 tile, 4 waves (64x64 each), global_load_lds staging, swizzled LDS.
// grid 4096: rt = bid>>2, ct = bid&3.
// ---------------------------------------------------------------------------
__global__ __launch_bounds__(256) void gemm_edge(
    const u16* __restrict__ A, const u16* __restrict__ Bt,
    u16* __restrict__ E) {
  __shared__ __align__(16) u16 Asm[8192];
  __shared__ __align__(16) u16 Bsm[8192];
  const int tid = threadIdx.x, lane = tid & 63, w = tid >> 6;
  const int m = lane & 15, q = lane >> 4;
  const int rt = blockIdx.x >> 2, ct = blockIdx.x & 3;
  const int wrow = (w & 1) * 64, wcol = (w >> 1) * 64;
  const char* Ab = (const char*)A + (long)rt * 131072;
  const char* Bb = (const char*)Bt + (long)ct * 65536;
  f32x4 acc[4][4];
#pragma unroll
  for (int r = 0; r < 4; ++r)
#pragma unroll
    for (int c = 0; c < 4; ++c) acc[r][c] = (f32x4){0.f, 0.f, 0.f, 0.f};

  for (int kc = 0; kc < 4; ++kc) {
#pragma unroll
    for (int t = 0; t < 4; ++t) {
      glds16(Ab + kc * 32768 + t * 4096 + tid * 16,
             (char*)Asm + t * 4096 + tid * 16);
      glds16(Bb + kc * 16384 + t * 4096 + tid * 16,
             (char*)Bsm + t * 4096 + tid * 16);
    }
    __syncthreads();
#pragma unroll
    for (int s = 0; s < 2; ++s) {
      const int ko2 = (s * 32 + q * 8) * 2;  // byte offset of k within row
      bf16x8 av[4], bv[4];
#pragma unroll
      for (int r = 0; r < 4; ++r) {
        int row = wrow + r * 16 + m;
        av[r] = *(const bf16x8*)((const char*)Asm + row * 128 +
                                 (ko2 ^ ((row & 7) * 16)));
      }
#pragma unroll
      for (int c = 0; c < 4; ++c) {
        int col = wcol + c * 16 + m;
        bv[c] = *(const bf16x8*)((const char*)Bsm + col * 128 +
                                 (ko2 ^ ((col & 7) * 16)));
      }
#pragma unroll
      for (int r = 0; r < 4; ++r)
#pragma unroll
        for (int c = 0; c < 4; ++c)
          acc[r][c] = __builtin_amdgcn_mfma_f32_16x16x32_bf16(
              av[r], bv[c], acc[r][c], 0, 0, 0);
    }
    __syncthreads();
  }
#pragma unroll
  for (int r = 0; r < 4; ++r)
#pragma unroll
    for (int c = 0; c < 4; ++c)
#pragma unroll
      for (int g = 0; g < 4; ++g) {
        long gr = (long)rt * 128 + wrow + r * 16 + q * 4 + g;
        int gc = ct * 128 + wcol + c * 16 + m;
        E[gr * 512 + gc] = f2bf(acc[r][c][g]);
      }
}

// ---------------------------------------------------------------------------
// Generic small GEMM (f32 A): C[M x Ntot] = A[M x K] * Bt[Ntot x K]^T
// ROWS-row x 256-col tile, 4 waves. ROWS=64: each wave 64x64.
// ---------------------------------------------------------------------------
template<int K, int ROWS, bool OUT_BF16>
__global__ __launch_bounds__(256) void gemm_mfma(
    const float* __restrict__ A, const u16* __restrict__ Bt,
    void* __restrict__ Cv, int Ntot) {
  constexpr int LD = 72;
  constexpr int CF = (ROWS == 128) ? 8 : 4;
  __shared__ __align__(16) u16 Asm[ROWS * LD];
  __shared__ __align__(16) u16 Bsm[256 * LD];
  const int tid = threadIdx.x;
  const int lane = tid & 63;
  const int w = tid >> 6;
  const int m = lane & 15;
  const int q = lane >> 4;
  const int wrow = (ROWS == 128) ? (w & 1) * 64 : 0;
  const int wcol = (ROWS == 128) ? (w >> 1) * 128 : w * 64;
  const long rowbase = (long)blockIdx.x * ROWS;
  const long colbase = (long)blockIdx.y * 256;
  f32x4 acc[4][CF];
#pragma unroll
  for (int r = 0; r < 4; ++r)
#pragma unroll
    for (int c = 0; c < CF; ++c) acc[r][c] = (f32x4){0.f, 0.f, 0.f, 0.f};

  for (int kc = 0; kc < K / 64; ++kc) {
    const int kb = kc * 64;
#pragma unroll
    for (int it = 0; it < ROWS / 16; ++it) {
      int f = it * 256 + tid;
      int r = f >> 4, c4 = (f & 15) * 4;
      float4 v = *(const float4*)(A + (rowbase + r) * K + kb + c4);
      ushort4 h;
      h.x = f2bf(v.x); h.y = f2bf(v.y); h.z = f2bf(v.z); h.w = f2bf(v.w);
      *(ushort4*)&Asm[r * LD + c4] = h;
    }
#pragma unroll
    for (int it = 0; it < 8; ++it) {
      int f = it * 256 + tid;
      int c = f >> 3, k8 = (f & 7) * 8;
      *(uint4*)&Bsm[c * LD + k8] =
          *(const uint4*)(Bt + (colbase + c) * K + kb + k8);
    }
    __syncthreads();
#pragma unroll
    for (int s = 0; s < 2; ++s) {
      const int ko = s * 32 + q * 8;
      bf16x8 av[4], bv[CF];
#pragma unroll
      for (int r = 0; r < 4; ++r)
        av[r] = *(const bf16x8*)&Asm[(wrow + r * 16 + m) * LD + ko];
#pragma unroll
      for (int c = 0; c < CF; ++c)
        bv[c] = *(const bf16x8*)&Bsm[(wcol + c * 16 + m) * LD + ko];
#pragma unroll
      for (int r = 0; r < 4; ++r)
#pragma unroll
        for (int c = 0; c < CF; ++c)
          acc[r][c] = __builtin_amdgcn_mfma_f32_16x16x32_bf16(
              av[r], bv[c], acc[r][c], 0, 0, 0);
    }
    __syncthreads();
  }
#pragma unroll
  for (int r = 0; r < 4; ++r)
#pragma unroll
    for (int c = 0; c < CF; ++c)
#pragma unroll
      for (int g = 0; g < 4; ++g) {
        long gr = rowbase + wrow + r * 16 + q * 4 + g;
        long gc = colbase + wcol + c * 16 + m;
        float v = acc[r][c][g];
        if (OUT_BF16) ((u16*)Cv)[gr * Ntot + gc] = f2bf(v);
        else          ((float*)Cv)[gr * Ntot + gc] = v;
      }
}

// ---------------------------------------------------------------------------
// Weight tables. BtE1/BtE2: tiled+swizzled [4 ct][4 kc][128 c][64 k].
// BtW0 [512][256], BtLoop [1536][256], BtFc3 [256][512]: plain col-major-K.
// ---------------------------------------------------------------------------
__global__ __launch_bounds__(256) void prep_bt(
    const float* __restrict__ weight, const float* __restrict__ align_lin,
    const float* __restrict__ fuse1_w, const float* __restrict__ fuse2_w,
    const float* __restrict__ fc1_w0, const float* __restrict__ fc2_w0,
    const float* __restrict__ fc3_w,
    u16* BtE1, u16* BtE2, u16* BtW0, u16* BtLoop, u16* BtFc3) {
  int g = blockIdx.x * 256 + threadIdx.x;  // 0..917503
  if (g < 262144) {
    int t = g & 131071;
    int col = t >> 8, k = t & 255;
    float v;
    if (g < 131072)
      v = (col < 256) ? fuse1_w[(256 + k) * 256 + col]
                      : fc1_w0[(512 + k) * 256 + (col - 256)];
    else
      v = (col < 256) ? fuse2_w[(256 + k) * 256 + col]
                      : fc2_w0[(512 + k) * 256 + (col - 256)];
    int ct = col >> 7, cc = col & 127, kc = k >> 6, kk = k & 63;
    u16* dst = (g < 131072) ? BtE1 : BtE2;
    dst[ct * 32768 + kc * 8192 + cc * 64 + (kk ^ ((cc & 7) * 8))] = f2bf(v);
  } else if (g < 393216) {
    int t = g - 262144;
    int c = t >> 8, k = t & 255;
    float v = (c < 256) ? weight[k * 256 + c] : align_lin[k * 256 + (c - 256)];
    BtW0[t] = f2bf(v);
  } else if (g < 786432) {
    int t = g - 393216;
    int c = t >> 8, k = t & 255;
    int seg = c >> 8, cc = c & 255;
    float v;
    if      (seg == 0) v = fuse1_w[k * 256 + cc];
    else if (seg == 1) v = fuse2_w[k * 256 + cc];
    else if (seg == 2) v = fc1_w0[k * 256 + cc];
    else if (seg == 3) v = fc1_w0[(256 + k) * 256 + cc];
    else if (seg == 4) v = fc2_w0[k * 256 + cc];
    else               v = fc2_w0[(256 + k) * 256 + cc];
    BtLoop[t] = f2bf(v);
  } else {
    int t = g - 786432;
    int c = t >> 9, k = t & 511;
    BtFc3[t] = f2bf(fc3_w[k * 256 + c]);
  }
}

__global__ __launch_bounds__(256) void relu0_kernel(const float* __restrict__ T0,
                                                    float* __restrict__ outb) {
  long r = blockIdx.x;
  int d = threadIdx.x;
  outb[r * 256 + d] = fmaxf(T0[r * 512 + d], 0.f);
}

// ---------------------------------------------------------------------------
// SelfAlignment (unchanged from R1)
// ---------------------------------------------------------------------------
__global__ __launch_bounds__(128) void align_kernel(
    const float* __restrict__ text, const float* __restrict__ T0,
    const float* __restrict__ textmask, const float* __restrict__ align_bias,
    float* __restrict__ outss) {
  const int bi = blockIdx.x;
  const int b = bi >> 7;
  const int tid = threadIdx.x;
  __shared__ float ta[256];
  __shared__ float pr[128];
  __shared__ float red[128];
  ta[tid]       = T0[(long)bi * 512 + 256 + tid];
  ta[tid + 128] = T0[(long)bi * 512 + 384 + tid];
  __syncthreads();
  const float* trow = text + (long)(b * 128 + tid) * 256;
  float dot = 0.f;
  for (int d = 0; d < 256; d += 4) {
    float4 t4 = *(const float4*)(trow + d);
    dot += t4.x * ta[d] + t4.y * ta[d + 1] + t4.z * ta[d + 2] + t4.w * ta[d + 3];
  }
  float logit = dot + (1.0f - textmask[b * 128 + tid]) * -1e20f;
  pr[tid] = logit;
  red[tid] = logit;
  __syncthreads();
  for (int off = 64; off; off >>= 1) {
    if (tid < off) red[tid] = fmaxf(red[tid], red[tid + off]);
    __syncthreads();
  }
  float mx = red[0];
  __syncthreads();
  float e = __expf(pr[tid] - mx);
  red[tid] = e;
  __syncthreads();
  for (int off = 64; off; off >>= 1) {
    if (tid < off) red[tid] += red[tid + off];
    __syncthreads();
  }
  float inv = 1.0f / red[0];
  __syncthreads();
  pr[tid] = e * inv;
  __syncthreads();
  const float mi = textmask[bi];
  for (int h = 0; h < 2; ++h) {
    int d = tid + h * 128;
    float s = 0.f;
    for (int j = 0; j < 128; ++j)
      s += pr[j] * text[(long)(b * 128 + j) * 256 + d];
    outss[(long)bi * 256 + d] = s * mi + align_bias[d];
  }
}

// ---------------------------------------------------------------------------
// Fused gate/aggregate, per (b,i). 256 thr = 4 waves.
// Lane (g16 = lane>>4, l16 = lane&15): group g16 owns j = w*32 + t*4 + g16,
// lane owns d-slice [l16*16, l16*16+16). Gate reduce = 4 shfl_xor (<16).
// ---------------------------------------------------------------------------
__global__ __launch_bounds__(256) void fused_gate(
    const u16* __restrict__ E1, const u16* __restrict__ E2,
    const float* __restrict__ P, const float* __restrict__ adj1,
    const float* __restrict__ adj2, const float* __restrict__ fc1w1,
    const float* __restrict__ fc1b1, const float* __restrict__ fc2w1,
    const float* __restrict__ fc2b1, float* __restrict__ OU12) {
  const int tid = threadIdx.x, lane = tid & 63, w = tid >> 6;
  const int g16 = lane >> 4, l16 = lane & 15;
  const int bi = blockIdx.x, b = bi >> 7;
  const int db = l16 * 16;
  const long rowi = (long)bi * 1536;
  const f32x16 w1v = *(const f32x16*)(fc1w1 + db);
  const f32x16 w2v = *(const f32x16*)(fc2w1 + db);
  const f32x16 ti1 = *(const f32x16*)(P + rowi + 512 + db);
  const f32x16 ti2 = *(const f32x16*)(P + rowi + 1024 + db);
  const float b1 = fc1b1[0], b2 = fc2b1[0];
  const long ebase = (long)bi * 65536;  // (b*16384 + i*128) * 512
  const int abase = bi * 128;
  f32x16 acc1, acc2;
#pragma unroll
  for (int dd = 0; dd < 16; ++dd) { acc1[dd] = 0.f; acc2[dd] = 0.f; }
  float da1 = 0.f, da2 = 0.f;

  for (int t = 0; t < 8; ++t) {
    const int j = w * 32 + t * 4 + g16;
    const long er = ebase + (long)j * 512;
    const long rowj = (long)(b * 128 + j) * 1536;
    f32x16 e1cf = unpack16(E1 + er + 256 + db);
    f32x16 e2cf = unpack16(E2 + er + 256 + db);
    f32x16 tj1 = *(const f32x16*)(P + rowj + 768 + db);
    f32x16 tj2 = *(const f32x16*)(P + rowj + 1280 + db);
    float a1 = adj1[abase + j], a2 = adj2[abase + j];
    float z1 = 0.f, z2 = 0.f;
#pragma unroll
    for (int dd = 0; dd < 16; ++dd) {
      z1 += fmaxf(ti1[dd] + tj1[dd] + e1cf[dd], 0.f) * w1v[dd];
      z2 += fmaxf(ti2[dd] + tj2[dd] + e2cf[dd], 0.f) * w2v[dd];
    }
#pragma unroll
    for (int off = 1; off < 16; off <<= 1) {
      z1 += __shfl_xor(z1, off);
      z2 += __shfl_xor(z2, off);
    }
    float s1 = a1 / (1.f + __expf(-(z1 + b1)));
    float s2 = a2 / (1.f + __expf(-(z2 + b2)));
    f32x16 e1ff = unpack16(E1 + er + db);
    f32x16 e2ff = unpack16(E2 + er + db);
    f32x16 of1 = *(const f32x16*)(P + rowj + db);
    f32x16 of2 = *(const f32x16*)(P + rowj + 256 + db);
#pragma unroll
    for (int dd = 0; dd < 16; ++dd) {
      acc1[dd] += s1 * fmaxf(of1[dd] + e1ff[dd], 0.f);
      acc2[dd] += s2 * fmaxf(of2[dd] + e2ff[dd], 0.f);
    }
    da1 += a1;
    da2 += a2;
  }

  __shared__ float redA[16][260];  // +4 pad: staggers banks across partials
  __shared__ float redB[16][260];
  __shared__ float dA[16], dB[16];
  const int p = w * 4 + g16;
#pragma unroll
  for (int v = 0; v < 4; ++v) {
    *(float4*)&redA[p][db + v * 4] =
        make_float4(acc1[v*4], acc1[v*4+1], acc1[v*4+2], acc1[v*4+3]);
    *(float4*)&redB[p][db + v * 4] =
        make_float4(acc2[v*4], acc2[v*4+1], acc2[v*4+2], acc2[v*4+3]);
  }
  if (l16 == 0) { dA[p] = da1; dB[p] = da2; }
  __syncthreads();
  float o1 = 0.f, o2 = 0.f, d1 = 1.f, d2 = 1.f;
#pragma unroll
  for (int pp = 0; pp < 16; ++pp) {
    o1 += redA[pp][tid];
    o2 += redB[pp][tid];
    d1 += dA[pp];
    d2 += dB[pp];
  }
  OU12[(long)bi * 512 + tid] = o1 / d1;
  OU12[(long)bi * 512 + 256 + tid] = o2 / d2;
}

// ---------------------------------------------------------------------------
// out = layernorm(relu(Y) + prev + bias) * gamma + beta
// ---------------------------------------------------------------------------
__global__ __launch_bounds__(256) void ln_kernel(
    const float* __restrict__ Y, const float* __restrict__ prev,
    const float* __restrict__ bias, const float* __restrict__ gamma,
    const float* __restrict__ beta, float* __restrict__ dst) {
  const int row = blockIdx.x, tid = threadIdx.x, lane = tid & 63, w = tid >> 6;
  const long idx = (long)row * 256 + tid;
  float v = fmaxf(Y[idx], 0.f) + prev[idx] + bias[tid];
  float s = v;
#pragma unroll
  for (int off = 32; off; off >>= 1) s += __shfl_xor(s, off);
  __shared__ float wsA[4], wsB[4];
  if (lane == 0) wsA[w] = s;
  __syncthreads();
  float mean = (wsA[0] + wsA[1] + wsA[2] + wsA[3]) * (1.0f / 256.0f);
  float c = v - mean;
  float s2 = c * c;
#pragma unroll
  for (int off = 32; off; off >>= 1) s2 += __shfl_xor(s2, off);
  if (lane == 0) wsB[w] = s2;
  __syncthreads();
  float var = (wsB[0] + wsB[1] + wsB[2] + wsB[3]) * (1.0f / 256.0f);
  dst[idx] = c * rsqrtf(var + 1e-5f) * gamma[tid] + beta[tid];
}

// ---------------------------------------------------------------------------
extern "C" void kernel_launch(void* const* d_in, const int* in_sizes, int n_in,
                              void* d_out, int out_size, void* d_ws, size_t ws_size,
                              hipStream_t stream) {
  const float* text      = (const float*)d_in[0];
  const float* adj1      = (const float*)d_in[1];
  const float* adj2      = (const float*)d_in[2];
  const float* edge1     = (const float*)d_in[3];
  const float* edge2     = (const float*)d_in[4];
  const float* textmask  = (const float*)d_in[5];
  const float* weight    = (const float*)d_in[6];
  const float* bias      = (const float*)d_in[7];
  const float* gamma     = (const float*)d_in[8];
  const float* beta      = (const float*)d_in[9];
  const float* fuse1_w   = (const float*)d_in[10];
  const float* fuse2_w   = (const float*)d_in[11];
  const float* fc3_w     = (const float*)d_in[12];
  const float* fc1_w0    = (const float*)d_in[13];
  const float* fc1_w1    = (const float*)d_in[14];
  const float* fc1_b1    = (const float*)d_in[15];
  const float* fc2_w0    = (const float*)d_in[16];
  const float* fc2_w1    = (const float*)d_in[17];
  const float* fc2_b1    = (const float*)d_in[18];
  const float* align_lin = (const float*)d_in[19];
  const float* align_bias= (const float*)d_in[20];
  float* outF = (float*)d_out;  // out: [0,262144), outss: [262144,524288)

  char* w8 = (char*)d_ws;
  u16* Ax   = (u16*)w8;                       // 64 MB (freed after edge GEMMs)
  u16* E1   = (u16*)(w8 + 67108864);          // 128 MB
  u16* E2   = (u16*)(w8 + 201326592);         // 128 MB
  u16* BtE1 = (u16*)(w8 + 335544320);
  u16* BtE2 = BtE1 + 131072;
  u16* BtW0 = BtE2 + 131072;
  u16* BtLoop = BtW0 + 131072;                // 1536 x 256
  u16* BtFc3  = BtLoop + 393216;              // 256 x 512
  // small f32 buffers live inside the Ax region (dead after edge GEMMs)
  float* P    = (float*)w8;                   // 1024 x 1536
  float* T0   = P + 1572864;                  // 1024 x 512
  float* OU12 = T0 + 524288;                  // 1024 x 512
  float* outb = OU12 + 524288;                // 1024 x 256
  float* Yb   = outb + 262144;                // 1024 x 256

  // 1) weight tables
  prep_bt<<<3584, 256, 0, stream>>>(weight, align_lin, fuse1_w, fuse2_w,
                                    fc1_w0, fc2_w0, fc3_w,
                                    BtE1, BtE2, BtW0, BtLoop, BtFc3);
  // 2) edge projections (loop-invariant): convert f32->bf16 tiled, then GEMM
  convert_edge<<<16384, 256, 0, stream>>>(edge1, Ax);
  gemm_edge<<<4096, 256, 0, stream>>>(Ax, BtE1, E1);
  convert_edge<<<16384, 256, 0, stream>>>(edge2, Ax);
  gemm_edge<<<4096, 256, 0, stream>>>(Ax, BtE2, E2);
  // 3) T0 = text @ [weight | align_lin]   (Ax region now reusable)
  gemm_mfma<256, 64, false><<<dim3(16, 2), 256, 0, stream>>>(text, BtW0, T0, 512);
  relu0_kernel<<<1024, 256, 0, stream>>>(T0, outb);
  // 4) self-alignment -> outss
  align_kernel<<<1024, 128, 0, stream>>>(text, T0, textmask, align_bias,
                                         outF + 262144);
  // 5) K = 3 GCN iterations
  for (int it = 0; it < 3; ++it) {
    gemm_mfma<256, 64, false><<<dim3(16, 6), 256, 0, stream>>>(outb, BtLoop, P, 1536);
    fused_gate<<<1024, 256, 0, stream>>>(E1, E2, P, adj1, adj2, fc1_w1, fc1_b1,
                                         fc2_w1, fc2_b1, OU12);
    gemm_mfma<512, 64, false><<<dim3(16, 1), 256, 0, stream>>>(OU12, BtFc3, Yb, 256);
    ln_kernel<<<1024, 256, 0, stream>>>(Yb, outb, bias, gamma, beta,
                                        (it == 2) ? outF : outb);
  }
}